// Round 17
// baseline (266.894 us; speedup 1.0000x reference)
//
#include <hip/hip_runtime.h>
#include <hip/hip_fp16.h>
#include <math.h>

#define DIM 64
#define CBSH 9                 // coarse bucket: 512 dst nodes
#define CBSZ (1 << CBSH)
#define CHUNK 4096             // edges per partition block

__device__ __forceinline__ float leaky(float e) { return e > 0.f ? e : 0.2f * e; }

// ---------------- CSR build (no global per-node atomics anywhere) ----------------
__global__ __launch_bounds__(256) void k_part_hist(
        const int* __restrict__ ei, int* __restrict__ hist2d,
        int E, int NPB, int NCB) {
    __shared__ int hist[256];
    int blk = blockIdx.x;
    int base = blk * CHUNK;
    int ecnt = min(CHUNK, E - base);
    for (int i = threadIdx.x; i < 256; i += 256) hist[i] = 0;
    __syncthreads();
    for (int i = threadIdx.x; i < ecnt; i += 256)
        atomicAdd(&hist[ei[E + base + i] >> CBSH], 1);
    __syncthreads();
    for (int cb = threadIdx.x; cb < NCB; cb += 256)
        hist2d[cb * NPB + blk] = hist[cb];
}

__global__ __launch_bounds__(512) void k_part_scan(
        int* __restrict__ hist2d, int* __restrict__ btot, int NPB) {
    __shared__ int tmp[512];
    int cb = blockIdx.x;
    int t = threadIdx.x;
    int v = (t < NPB) ? hist2d[cb * NPB + t] : 0;
    tmp[t] = v;
    __syncthreads();
    for (int off = 1; off < 512; off <<= 1) {
        int u = (t >= off) ? tmp[t - off] : 0;
        __syncthreads();
        tmp[t] += u;
        __syncthreads();
    }
    if (t < NPB) hist2d[cb * NPB + t] = tmp[t] - v;   // relative exclusive
    if (t == NPB - 1) btot[cb] = tmp[t];              // bucket edge total
}

__global__ __launch_bounds__(256) void k_ebase(
        const int* __restrict__ btot, int* __restrict__ ebase,
        int* __restrict__ row_ptr, int NCB, int n, int E) {
    __shared__ int tmp[256];
    int t = threadIdx.x;
    int v = (t < NCB) ? btot[t] : 0;
    tmp[t] = v;
    __syncthreads();
    for (int off = 1; off < 256; off <<= 1) {
        int u = (t >= off) ? tmp[t - off] : 0;
        __syncthreads();
        tmp[t] += u;
        __syncthreads();
    }
    if (t < NCB) ebase[t] = tmp[t] - v;
    if (t == NCB - 1) ebase[NCB] = tmp[t];   // == E
    if (t == 0) row_ptr[n] = E + n;
}

// P3: packed 4B: (s << CBSH) | (d & (CBSZ-1)).  s < 2^17, local d < 2^9.
__global__ __launch_bounds__(256) void k_part_scatter(
        const int* __restrict__ ei, const int* __restrict__ hist2d,
        const int* __restrict__ ebase, int* __restrict__ part,
        int E, int NPB, int NCB) {
    __shared__ int gb[256];
    __shared__ int cnt[256];
    int blk = blockIdx.x;
    int base = blk * CHUNK;
    int ecnt = min(CHUNK, E - base);
    for (int i = threadIdx.x; i < NCB; i += 256) {
        gb[i] = ebase[i] + hist2d[i * NPB + blk];
        cnt[i] = 0;
    }
    __syncthreads();
    for (int i = threadIdx.x; i < ecnt; i += 256) {
        int s = ei[base + i];
        int d = ei[E + base + i];
        int cb = d >> CBSH;
        int off = atomicAdd(&cnt[cb], 1);  // LDS ticket within run
        part[gb[cb] + off] = (s << CBSH) | (d & (CBSZ - 1));
    }
}

__global__ __launch_bounds__(256) void k_bucket_scatter(
        const int* __restrict__ ebase, const int* __restrict__ part,
        int* __restrict__ row_ptr, int* __restrict__ csr, int n) {
    __shared__ int arr[CBSZ];
    __shared__ int lcur[CBSZ];
    int cb = blockIdx.x;
    int d0 = cb << CBSH;
    int nb = min(CBSZ, n - d0);
    int t = threadIdx.x;
    int ebeg = ebase[cb], eend = ebase[cb + 1];
    arr[t] = 0; arr[t + 256] = 0;
    __syncthreads();
    for (int p = ebeg + t; p < eend; p += 256)
        atomicAdd(&arr[part[p] & (CBSZ - 1)], 1);
    __syncthreads();
    int v0 = (t < nb) ? arr[t] + 1 : 0;
    int v1 = (t + 256 < nb) ? arr[t + 256] + 1 : 0;
    __syncthreads();
    arr[t] = v0; arr[t + 256] = v1;
    __syncthreads();
    for (int off = 1; off < 512; off <<= 1) {
        int a0 = (t >= off) ? arr[t - off] : 0;
        int a1 = (t + 256 >= off) ? arr[t + 256 - off] : 0;
        __syncthreads();
        arr[t] += a0; arr[t + 256] += a1;
        __syncthreads();
    }
    int nbase = ebeg + d0;
    if (t < nb) {
        int rp = nbase + arr[t] - v0;
        row_ptr[d0 + t] = rp;
        csr[rp] = d0 + t;          // self loop at slot 0
        lcur[t] = rp + 1;
    }
    if (t + 256 < nb) {
        int rp = nbase + arr[t + 256] - v1;
        row_ptr[d0 + t + 256] = rp;
        csr[rp] = d0 + t + 256;
        lcur[t + 256] = rp + 1;
    }
    __syncthreads();
    for (int p = ebeg + t; p < eend; p += 256) {
        int v = part[p];
        int slot = atomicAdd(&lcur[v & (CBSZ - 1)], 1);
        csr[slot] = v >> CBSH;
    }
}

// ---------------- per-layer: K-tiled LDS GEMM + attention projections ----------------
// h stored fp16. FP16IN: input activations are fp16 with relu folded in
// (layers 1-2); else fp32 no-relu (layer 0).
template <int FIN, bool FP16IN>
__global__ __launch_bounds__(256, 4) void k_gemm_al(
        const void* __restrict__ xin_,
        const float* __restrict__ W,
        const float* __restrict__ as_, const float* __restrict__ ad_,
        __half* __restrict__ h, float* __restrict__ als, float* __restrict__ ald,
        int n) {
    constexpr int KT = 64;
    constexpr int BM = 64;
    __shared__ float ws[KT * 64];        // [k][col]
    __shared__ float xs[BM * (KT + 1)];  // [row][k], stride 65

    const int tid = threadIdx.x;
    const int row0 = blockIdx.x * BM;
    const int rt = tid >> 4, ct = tid & 15;
    const int r0 = rt * 4, c0 = ct * 4;

    float acc[4][4];
#pragma unroll
    for (int i = 0; i < 4; ++i)
#pragma unroll
        for (int j = 0; j < 4; ++j) acc[i][j] = 0.f;

    for (int kt = 0; kt < FIN; kt += KT) {
#pragma unroll
        for (int p = 0; p < KT * 16 / 256; ++p) {
            int i = tid + p * 256;
            *reinterpret_cast<float4*>(&ws[i * 4]) =
                *reinterpret_cast<const float4*>(&W[kt * 64 + i * 4]);
        }
        if constexpr (FP16IN) {
            // FIN==64, single kt. 8-half (16B = uint4) chunks: r=i>>3, kq=i&7.
            const __half* xin = (const __half*)xin_;
#pragma unroll
            for (int p = 0; p < BM * (KT / 8) / 256; ++p) {
                int i = tid + p * 256;
                int r = i >> 3;
                int kq = i & 7;
                int grow = row0 + r;
                uint4 raw = make_uint4(0u, 0u, 0u, 0u);   // 16B = 8 halves
                if (grow < n)
                    raw = *reinterpret_cast<const uint4*>(&xin[(size_t)grow * FIN + kq * 8]);
                const __half2* hp = reinterpret_cast<const __half2*>(&raw);
                float* dst = &xs[r * (KT + 1) + kq * 8];
#pragma unroll
                for (int u = 0; u < 4; ++u) {
                    float2 f = __half22float2(hp[u]);
                    dst[2 * u]     = fmaxf(f.x, 0.f);   // relu folded
                    dst[2 * u + 1] = fmaxf(f.y, 0.f);
                }
            }
        } else {
            const float* xin = (const float*)xin_;
#pragma unroll
            for (int p = 0; p < BM * (KT / 4) / 256; ++p) {
                int i = tid + p * 256;
                int r = i >> 4;
                int kq = i & 15;
                int grow = row0 + r;
                float4 v = make_float4(0.f, 0.f, 0.f, 0.f);
                if (grow < n)
                    v = *reinterpret_cast<const float4*>(&xin[(size_t)grow * FIN + kt + kq * 4]);
                float* dst = &xs[r * (KT + 1) + kq * 4];
                dst[0] = v.x; dst[1] = v.y; dst[2] = v.z; dst[3] = v.w;
            }
        }
        __syncthreads();

#pragma unroll 4
        for (int k = 0; k < KT; ++k) {
            float4 wv = *reinterpret_cast<const float4*>(&ws[k * 64 + c0]);
            float xv0 = xs[(r0 + 0) * (KT + 1) + k];
            float xv1 = xs[(r0 + 1) * (KT + 1) + k];
            float xv2 = xs[(r0 + 2) * (KT + 1) + k];
            float xv3 = xs[(r0 + 3) * (KT + 1) + k];
            acc[0][0] = fmaf(xv0, wv.x, acc[0][0]);
            acc[0][1] = fmaf(xv0, wv.y, acc[0][1]);
            acc[0][2] = fmaf(xv0, wv.z, acc[0][2]);
            acc[0][3] = fmaf(xv0, wv.w, acc[0][3]);
            acc[1][0] = fmaf(xv1, wv.x, acc[1][0]);
            acc[1][1] = fmaf(xv1, wv.y, acc[1][1]);
            acc[1][2] = fmaf(xv1, wv.z, acc[1][2]);
            acc[1][3] = fmaf(xv1, wv.w, acc[1][3]);
            acc[2][0] = fmaf(xv2, wv.x, acc[2][0]);
            acc[2][1] = fmaf(xv2, wv.y, acc[2][1]);
            acc[2][2] = fmaf(xv2, wv.z, acc[2][2]);
            acc[2][3] = fmaf(xv2, wv.w, acc[2][3]);
            acc[3][0] = fmaf(xv3, wv.x, acc[3][0]);
            acc[3][1] = fmaf(xv3, wv.y, acc[3][1]);
            acc[3][2] = fmaf(xv3, wv.z, acc[3][2]);
            acc[3][3] = fmaf(xv3, wv.w, acc[3][3]);
        }
        __syncthreads();
    }

    float4 asv = *reinterpret_cast<const float4*>(&as_[c0]);
    float4 adv = *reinterpret_cast<const float4*>(&ad_[c0]);
#pragma unroll
    for (int i = 0; i < 4; ++i) {
        int grow = row0 + r0 + i;
        if (grow < n) {
            __half2 p0 = __floats2half2_rn(acc[i][0], acc[i][1]);
            __half2 p1 = __floats2half2_rn(acc[i][2], acc[i][3]);
            uint2 pk = make_uint2(*reinterpret_cast<unsigned*>(&p0),
                                  *reinterpret_cast<unsigned*>(&p1));
            *reinterpret_cast<uint2*>(&h[(size_t)grow * 64 + c0]) = pk;  // 4 halves = 8B
        }
        float ps = acc[i][0] * asv.x + acc[i][1] * asv.y +
                   acc[i][2] * asv.z + acc[i][3] * asv.w;
        float pd = acc[i][0] * adv.x + acc[i][1] * adv.y +
                   acc[i][2] * adv.z + acc[i][3] * adv.w;
#pragma unroll
        for (int off = 1; off < 16; off <<= 1) {
            ps += __shfl_xor(ps, off);
            pd += __shfl_xor(pd, off);
        }
        if (ct == 0 && grow < n) { als[grow] = ps; ald[grow] = pd; }
    }
}

// ---------------- per-layer: fused softmax + aggregation, half-wave per node ----------------
// Lanes 0-31 = node A, 32-63 = node B. No max subtraction (|logit| small).
// Pipelined: per 32-edge chunk, csr is loaded, s broadcast, and the first 2
// batches (16 rows) of h-loads are ISSUED before the als gather + exp + sum
// reduce -- the weight math hides the h-load miss latency instead of
// serializing in front of it. Consume batch b while batch b+2 is in flight.
template <bool FP16OUT>
__global__ __launch_bounds__(256) void k_node_aggr(
        const int* __restrict__ row_ptr, const int* __restrict__ csr,
        const float* __restrict__ als, const float* __restrict__ ald,
        const __half* __restrict__ h, const float* __restrict__ bias,
        void* __restrict__ out_, int n) {
    const int lane = threadIdx.x & 63;
    const int hw = lane >> 5;        // node slot within wave
    const int l = lane & 31;         // lane within half-wave
    const int node = blockIdx.x * 8 + ((threadIdx.x >> 6) << 1) + hw;
    if (node >= n) return;
    int beg = row_ptr[node];
    int deg = row_ptr[node + 1] - beg;
    float adv = ald[node];
    float ssum = 0.f;
    float accx = 0.f, accy = 0.f;
    const int sbase = hw << 5;       // shfl base for this half-wave

    for (int c0 = 0; c0 < deg; c0 += 32) {
        int cn = min(32, deg - c0);
        int s_l = 0;
        if (l < cn) s_l = csr[beg + c0 + l];
        int cn8 = (cn + 7) & ~7;

        __half2 A0[8], A1[8], A2[8], A3[8];
        float w_l;

#define LOADB(Ab, J)                                                         \
        {                                                                    \
            _Pragma("unroll")                                                \
            for (int k = 0; k < 8; ++k) {                                    \
                int sk = __shfl(s_l, sbase + (J) + k);                       \
                Ab[k] = *reinterpret_cast<const __half2*>(                   \
                    &h[(size_t)sk * DIM + 2 * l]);                           \
            }                                                                \
        }
#define CONSB(Ab, J)                                                         \
        {                                                                    \
            _Pragma("unroll")                                                \
            for (int k = 0; k < 8; ++k) {                                    \
                float wk = __shfl(w_l, sbase + (J) + k);                     \
                float2 fk = __half22float2(Ab[k]);                           \
                accx = fmaf(wk, fk.x, accx);                                 \
                accy = fmaf(wk, fk.y, accy);                                 \
            }                                                                \
        }

        // issue 2 batches of h-row loads first (depend only on s):
        LOADB(A0, 0);
        if (cn8 > 8) LOADB(A1, 8);

        // weight math overlaps the in-flight loads
        w_l = 0.f;
        if (l < cn) w_l = __expf(leaky(als[s_l] + adv));   // no max subtraction
        float cs = w_l;
#pragma unroll
        for (int off = 16; off; off >>= 1) cs += __shfl_xor(cs, off);
        ssum += cs;

        CONSB(A0, 0);
        if (cn8 > 16) LOADB(A2, 16);
        if (cn8 > 8)  CONSB(A1, 8);
        if (cn8 > 24) LOADB(A3, 24);
        if (cn8 > 16) CONSB(A2, 16);
        if (cn8 > 24) CONSB(A3, 24);
#undef LOADB
#undef CONSB
    }

    float inv = 1.f / ssum;
    float ox = accx * inv + bias[2 * l];
    float oy = accy * inv + bias[2 * l + 1];
    if constexpr (FP16OUT) {
        __half* out = (__half*)out_;
        *reinterpret_cast<__half2*>(&out[(size_t)node * DIM + 2 * l]) =
            __floats2half2_rn(ox, oy);
    } else {
        float* out = (float*)out_;
        *reinterpret_cast<float2*>(&out[(size_t)node * DIM + 2 * l]) =
            make_float2(ox, oy);
    }
}

extern "C" void kernel_launch(void* const* d_in, const int* in_sizes, int n_in,
                              void* d_out, int out_size, void* d_ws, size_t ws_size,
                              hipStream_t stream) {
    const float* x = (const float*)d_in[0];
    const int* ei = (const int*)d_in[1];   // harness converts integer inputs to int32
    const int n = out_size / DIM;          // 100000
    const int E = in_sizes[1] / 2;         // 1600000
    const int total_edges = E + n;
    const int NCB = (n + CBSZ - 1) >> CBSH;      // 196 coarse buckets (<=256)
    const int NPB = (E + CHUNK - 1) / CHUNK;     // 391 partition blocks (<=512)

    const float *W[3], *as_[3], *ad_[3], *b[3];
    for (int l = 0; l < 3; ++l) {
        W[l]  = (const float*)d_in[2 + 4 * l];
        as_[l] = (const float*)d_in[3 + 4 * l];
        ad_[l] = (const float*)d_in[4 + 4 * l];
        b[l]  = (const float*)d_in[5 + 4 * l];
    }

    // workspace carve (256B aligned).
    char* ws = (char*)d_ws;
    size_t off = 0;
    auto alloc = [&](size_t bytes) {
        void* p = ws + off;
        off = (off + bytes + 255) & ~(size_t)255;
        return p;
    };
    int* row_ptr  = (int*)alloc((size_t)(n + 1) * 4);
    int* hist2d   = (int*)alloc((size_t)NCB * NPB * 4);
    int* btot     = (int*)alloc(256 * 4);
    int* ebase    = (int*)alloc(257 * 4);
    int* csr      = (int*)alloc((size_t)total_edges * 4);
    int* part     = (int*)alloc((size_t)E * 4);
    __half* h     = (__half*)alloc((size_t)n * DIM * 2);
    __half* bufh  = (__half*)alloc((size_t)n * DIM * 2);  // fp16 inter-layer acts
    float* als    = (float*)alloc((size_t)n * 4);
    float* ald    = (float*)alloc((size_t)n * 4);

    // ---- CSR build (once; shared by all 3 layers) ----
    k_part_hist<<<NPB, 256, 0, stream>>>(ei, hist2d, E, NPB, NCB);
    k_part_scan<<<NCB, 512, 0, stream>>>(hist2d, btot, NPB);
    k_ebase<<<1, 256, 0, stream>>>(btot, ebase, row_ptr, NCB, n, E);
    k_part_scatter<<<NPB, 256, 0, stream>>>(ei, hist2d, ebase, part, E, NPB, NCB);
    k_bucket_scatter<<<NCB, 256, 0, stream>>>(ebase, part, row_ptr, csr, n);

    // ---- 3 GAT layers ----
    const int aggr_blocks = (n + 7) / 8;   // 8 nodes (half-waves) per 256-thread block
    const int gemm_blocks = (n + 63) / 64;

    // layer 0: fp32 input (no relu) -> fp16 activations
    k_gemm_al<128, false><<<gemm_blocks, 256, 0, stream>>>(
        x, W[0], as_[0], ad_[0], h, als, ald, n);
    k_node_aggr<true><<<aggr_blocks, 256, 0, stream>>>(
        row_ptr, csr, als, ald, h, b[0], bufh, n);
    // layer 1: fp16 input (relu folded) -> fp16 activations
    k_gemm_al<64, true><<<gemm_blocks, 256, 0, stream>>>(
        bufh, W[1], as_[1], ad_[1], h, als, ald, n);
    k_node_aggr<true><<<aggr_blocks, 256, 0, stream>>>(
        row_ptr, csr, als, ald, h, b[1], bufh, n);
    // layer 2: fp16 input (relu folded) -> fp32 d_out
    k_gemm_al<64, true><<<gemm_blocks, 256, 0, stream>>>(
        bufh, W[2], as_[2], ad_[2], h, als, ald, n);
    k_node_aggr<false><<<aggr_blocks, 256, 0, stream>>>(
        row_ptr, csr, als, ald, h, b[2], d_out, n);
}

// Round 18
// 235.546 us; speedup vs baseline: 1.1331x; 1.1331x over previous
//
#include <hip/hip_runtime.h>
#include <hip/hip_fp16.h>
#include <math.h>

#define DIM 64
#define CBSH 9                 // coarse bucket: 512 dst nodes
#define CBSZ (1 << CBSH)
#define CHUNK 4096             // edges per partition block

__device__ __forceinline__ float leaky(float e) { return e > 0.f ? e : 0.2f * e; }

// ---------------- CSR build (no global per-node atomics anywhere) ----------------
__global__ __launch_bounds__(256) void k_part_hist(
        const int* __restrict__ ei, int* __restrict__ hist2d,
        int E, int NPB, int NCB) {
    __shared__ int hist[256];
    int blk = blockIdx.x;
    int base = blk * CHUNK;
    int ecnt = min(CHUNK, E - base);
    for (int i = threadIdx.x; i < 256; i += 256) hist[i] = 0;
    __syncthreads();
    for (int i = threadIdx.x; i < ecnt; i += 256)
        atomicAdd(&hist[ei[E + base + i] >> CBSH], 1);
    __syncthreads();
    for (int cb = threadIdx.x; cb < NCB; cb += 256)
        hist2d[cb * NPB + blk] = hist[cb];
}

__global__ __launch_bounds__(512) void k_part_scan(
        int* __restrict__ hist2d, int* __restrict__ btot, int NPB) {
    __shared__ int tmp[512];
    int cb = blockIdx.x;
    int t = threadIdx.x;
    int v = (t < NPB) ? hist2d[cb * NPB + t] : 0;
    tmp[t] = v;
    __syncthreads();
    for (int off = 1; off < 512; off <<= 1) {
        int u = (t >= off) ? tmp[t - off] : 0;
        __syncthreads();
        tmp[t] += u;
        __syncthreads();
    }
    if (t < NPB) hist2d[cb * NPB + t] = tmp[t] - v;   // relative exclusive
    if (t == NPB - 1) btot[cb] = tmp[t];              // bucket edge total
}

__global__ __launch_bounds__(256) void k_ebase(
        const int* __restrict__ btot, int* __restrict__ ebase,
        int* __restrict__ row_ptr, int NCB, int n, int E) {
    __shared__ int tmp[256];
    int t = threadIdx.x;
    int v = (t < NCB) ? btot[t] : 0;
    tmp[t] = v;
    __syncthreads();
    for (int off = 1; off < 256; off <<= 1) {
        int u = (t >= off) ? tmp[t - off] : 0;
        __syncthreads();
        tmp[t] += u;
        __syncthreads();
    }
    if (t < NCB) ebase[t] = tmp[t] - v;
    if (t == NCB - 1) ebase[NCB] = tmp[t];   // == E
    if (t == 0) row_ptr[n] = E + n;
}

// P3: packed 4B: (s << CBSH) | (d & (CBSZ-1)).  s < 2^17, local d < 2^9.
__global__ __launch_bounds__(256) void k_part_scatter(
        const int* __restrict__ ei, const int* __restrict__ hist2d,
        const int* __restrict__ ebase, int* __restrict__ part,
        int E, int NPB, int NCB) {
    __shared__ int gb[256];
    __shared__ int cnt[256];
    int blk = blockIdx.x;
    int base = blk * CHUNK;
    int ecnt = min(CHUNK, E - base);
    for (int i = threadIdx.x; i < NCB; i += 256) {
        gb[i] = ebase[i] + hist2d[i * NPB + blk];
        cnt[i] = 0;
    }
    __syncthreads();
    for (int i = threadIdx.x; i < ecnt; i += 256) {
        int s = ei[base + i];
        int d = ei[E + base + i];
        int cb = d >> CBSH;
        int off = atomicAdd(&cnt[cb], 1);  // LDS ticket within run
        part[gb[cb] + off] = (s << CBSH) | (d & (CBSZ - 1));
    }
}

__global__ __launch_bounds__(256) void k_bucket_scatter(
        const int* __restrict__ ebase, const int* __restrict__ part,
        int* __restrict__ row_ptr, int* __restrict__ csr, int n) {
    __shared__ int arr[CBSZ];
    __shared__ int lcur[CBSZ];
    int cb = blockIdx.x;
    int d0 = cb << CBSH;
    int nb = min(CBSZ, n - d0);
    int t = threadIdx.x;
    int ebeg = ebase[cb], eend = ebase[cb + 1];
    arr[t] = 0; arr[t + 256] = 0;
    __syncthreads();
    for (int p = ebeg + t; p < eend; p += 256)
        atomicAdd(&arr[part[p] & (CBSZ - 1)], 1);
    __syncthreads();
    int v0 = (t < nb) ? arr[t] + 1 : 0;
    int v1 = (t + 256 < nb) ? arr[t + 256] + 1 : 0;
    __syncthreads();
    arr[t] = v0; arr[t + 256] = v1;
    __syncthreads();
    for (int off = 1; off < 512; off <<= 1) {
        int a0 = (t >= off) ? arr[t - off] : 0;
        int a1 = (t + 256 >= off) ? arr[t + 256 - off] : 0;
        __syncthreads();
        arr[t] += a0; arr[t + 256] += a1;
        __syncthreads();
    }
    int nbase = ebeg + d0;
    if (t < nb) {
        int rp = nbase + arr[t] - v0;
        row_ptr[d0 + t] = rp;
        csr[rp] = d0 + t;          // self loop at slot 0
        lcur[t] = rp + 1;
    }
    if (t + 256 < nb) {
        int rp = nbase + arr[t + 256] - v1;
        row_ptr[d0 + t + 256] = rp;
        csr[rp] = d0 + t + 256;
        lcur[t + 256] = rp + 1;
    }
    __syncthreads();
    for (int p = ebeg + t; p < eend; p += 256) {
        int v = part[p];
        int slot = atomicAdd(&lcur[v & (CBSZ - 1)], 1);
        csr[slot] = v >> CBSH;
    }
}

// ---------------- per-layer: K-tiled LDS GEMM + attention projections ----------------
// h stored fp16. FP16IN: input activations are fp16 with relu folded in
// (layers 1-2); else fp32 no-relu (layer 0).
template <int FIN, bool FP16IN>
__global__ __launch_bounds__(256, 4) void k_gemm_al(
        const void* __restrict__ xin_,
        const float* __restrict__ W,
        const float* __restrict__ as_, const float* __restrict__ ad_,
        __half* __restrict__ h, float* __restrict__ als, float* __restrict__ ald,
        int n) {
    constexpr int KT = 64;
    constexpr int BM = 64;
    __shared__ float ws[KT * 64];        // [k][col]
    __shared__ float xs[BM * (KT + 1)];  // [row][k], stride 65

    const int tid = threadIdx.x;
    const int row0 = blockIdx.x * BM;
    const int rt = tid >> 4, ct = tid & 15;
    const int r0 = rt * 4, c0 = ct * 4;

    float acc[4][4];
#pragma unroll
    for (int i = 0; i < 4; ++i)
#pragma unroll
        for (int j = 0; j < 4; ++j) acc[i][j] = 0.f;

    for (int kt = 0; kt < FIN; kt += KT) {
#pragma unroll
        for (int p = 0; p < KT * 16 / 256; ++p) {
            int i = tid + p * 256;
            *reinterpret_cast<float4*>(&ws[i * 4]) =
                *reinterpret_cast<const float4*>(&W[kt * 64 + i * 4]);
        }
        if constexpr (FP16IN) {
            // FIN==64, single kt. 8-half (16B = uint4) chunks: r=i>>3, kq=i&7.
            const __half* xin = (const __half*)xin_;
#pragma unroll
            for (int p = 0; p < BM * (KT / 8) / 256; ++p) {
                int i = tid + p * 256;
                int r = i >> 3;
                int kq = i & 7;
                int grow = row0 + r;
                uint4 raw = make_uint4(0u, 0u, 0u, 0u);   // 16B = 8 halves
                if (grow < n)
                    raw = *reinterpret_cast<const uint4*>(&xin[(size_t)grow * FIN + kq * 8]);
                const __half2* hp = reinterpret_cast<const __half2*>(&raw);
                float* dst = &xs[r * (KT + 1) + kq * 8];
#pragma unroll
                for (int u = 0; u < 4; ++u) {
                    float2 f = __half22float2(hp[u]);
                    dst[2 * u]     = fmaxf(f.x, 0.f);   // relu folded
                    dst[2 * u + 1] = fmaxf(f.y, 0.f);
                }
            }
        } else {
            const float* xin = (const float*)xin_;
#pragma unroll
            for (int p = 0; p < BM * (KT / 4) / 256; ++p) {
                int i = tid + p * 256;
                int r = i >> 4;
                int kq = i & 15;
                int grow = row0 + r;
                float4 v = make_float4(0.f, 0.f, 0.f, 0.f);
                if (grow < n)
                    v = *reinterpret_cast<const float4*>(&xin[(size_t)grow * FIN + kt + kq * 4]);
                float* dst = &xs[r * (KT + 1) + kq * 4];
                dst[0] = v.x; dst[1] = v.y; dst[2] = v.z; dst[3] = v.w;
            }
        }
        __syncthreads();

#pragma unroll 4
        for (int k = 0; k < KT; ++k) {
            float4 wv = *reinterpret_cast<const float4*>(&ws[k * 64 + c0]);
            float xv0 = xs[(r0 + 0) * (KT + 1) + k];
            float xv1 = xs[(r0 + 1) * (KT + 1) + k];
            float xv2 = xs[(r0 + 2) * (KT + 1) + k];
            float xv3 = xs[(r0 + 3) * (KT + 1) + k];
            acc[0][0] = fmaf(xv0, wv.x, acc[0][0]);
            acc[0][1] = fmaf(xv0, wv.y, acc[0][1]);
            acc[0][2] = fmaf(xv0, wv.z, acc[0][2]);
            acc[0][3] = fmaf(xv0, wv.w, acc[0][3]);
            acc[1][0] = fmaf(xv1, wv.x, acc[1][0]);
            acc[1][1] = fmaf(xv1, wv.y, acc[1][1]);
            acc[1][2] = fmaf(xv1, wv.z, acc[1][2]);
            acc[1][3] = fmaf(xv1, wv.w, acc[1][3]);
            acc[2][0] = fmaf(xv2, wv.x, acc[2][0]);
            acc[2][1] = fmaf(xv2, wv.y, acc[2][1]);
            acc[2][2] = fmaf(xv2, wv.z, acc[2][2]);
            acc[2][3] = fmaf(xv2, wv.w, acc[2][3]);
            acc[3][0] = fmaf(xv3, wv.x, acc[3][0]);
            acc[3][1] = fmaf(xv3, wv.y, acc[3][1]);
            acc[3][2] = fmaf(xv3, wv.z, acc[3][2]);
            acc[3][3] = fmaf(xv3, wv.w, acc[3][3]);
        }
        __syncthreads();
    }

    float4 asv = *reinterpret_cast<const float4*>(&as_[c0]);
    float4 adv = *reinterpret_cast<const float4*>(&ad_[c0]);
#pragma unroll
    for (int i = 0; i < 4; ++i) {
        int grow = row0 + r0 + i;
        if (grow < n) {
            __half2 p0 = __floats2half2_rn(acc[i][0], acc[i][1]);
            __half2 p1 = __floats2half2_rn(acc[i][2], acc[i][3]);
            uint2 pk = make_uint2(*reinterpret_cast<unsigned*>(&p0),
                                  *reinterpret_cast<unsigned*>(&p1));
            *reinterpret_cast<uint2*>(&h[(size_t)grow * 64 + c0]) = pk;  // 4 halves = 8B
        }
        float ps = acc[i][0] * asv.x + acc[i][1] * asv.y +
                   acc[i][2] * asv.z + acc[i][3] * asv.w;
        float pd = acc[i][0] * adv.x + acc[i][1] * adv.y +
                   acc[i][2] * adv.z + acc[i][3] * adv.w;
#pragma unroll
        for (int off = 1; off < 16; off <<= 1) {
            ps += __shfl_xor(ps, off);
            pd += __shfl_xor(pd, off);
        }
        if (ct == 0 && grow < n) { als[grow] = ps; ald[grow] = pd; }
    }
}

// ---------------- per-layer: fused softmax + aggregation, half-wave per node ----------------
// Lanes 0-31 = node A, 32-63 = node B. No max subtraction (|logit| small).
// Gather: 32 lanes x __half2 = one 128B row per load; unroll 8 rows/node/iter
// -> 16 row-loads in flight per wave. FP16OUT: inter-layer activations fp16.
// (round-16 shape: r13 wider-loads, r17 explicit pipelining both regressed --
// TLP at ~55% occupancy already saturates the line-transaction service.)
template <bool FP16OUT>
__global__ __launch_bounds__(256) void k_node_aggr(
        const int* __restrict__ row_ptr, const int* __restrict__ csr,
        const float* __restrict__ als, const float* __restrict__ ald,
        const __half* __restrict__ h, const float* __restrict__ bias,
        void* __restrict__ out_, int n) {
    const int lane = threadIdx.x & 63;
    const int hw = lane >> 5;        // node slot within wave
    const int l = lane & 31;         // lane within half-wave
    const int node = blockIdx.x * 8 + ((threadIdx.x >> 6) << 1) + hw;
    if (node >= n) return;
    int beg = row_ptr[node];
    int deg = row_ptr[node + 1] - beg;
    float adv = ald[node];
    float ssum = 0.f;
    float accx = 0.f, accy = 0.f;
    const int sbase = hw << 5;       // shfl base for this half-wave
    for (int c0 = 0; c0 < deg; c0 += 32) {
        int cn = min(32, deg - c0);
        int s_l = 0;
        float w_l = 0.f;
        if (l < cn) {
            s_l = csr[beg + c0 + l];
            w_l = __expf(leaky(als[s_l] + adv));   // no max subtraction
        }
        float cs = w_l;
#pragma unroll
        for (int off = 16; off; off >>= 1) cs += __shfl_xor(cs, off);
        ssum += cs;
        int cn8 = (cn + 7) & ~7;
        for (int j = 0; j < cn8; j += 8) {
            int   s0 = __shfl(s_l, sbase + j),     s1 = __shfl(s_l, sbase + j + 1);
            int   s2 = __shfl(s_l, sbase + j + 2), s3 = __shfl(s_l, sbase + j + 3);
            int   s4 = __shfl(s_l, sbase + j + 4), s5 = __shfl(s_l, sbase + j + 5);
            int   s6 = __shfl(s_l, sbase + j + 6), s7 = __shfl(s_l, sbase + j + 7);
            float w0 = __shfl(w_l, sbase + j),     w1 = __shfl(w_l, sbase + j + 1);
            float w2 = __shfl(w_l, sbase + j + 2), w3 = __shfl(w_l, sbase + j + 3);
            float w4 = __shfl(w_l, sbase + j + 4), w5 = __shfl(w_l, sbase + j + 5);
            float w6 = __shfl(w_l, sbase + j + 6), w7 = __shfl(w_l, sbase + j + 7);
            __half2 a0 = *reinterpret_cast<const __half2*>(&h[(size_t)s0 * DIM + 2 * l]);
            __half2 a1 = *reinterpret_cast<const __half2*>(&h[(size_t)s1 * DIM + 2 * l]);
            __half2 a2 = *reinterpret_cast<const __half2*>(&h[(size_t)s2 * DIM + 2 * l]);
            __half2 a3 = *reinterpret_cast<const __half2*>(&h[(size_t)s3 * DIM + 2 * l]);
            __half2 a4 = *reinterpret_cast<const __half2*>(&h[(size_t)s4 * DIM + 2 * l]);
            __half2 a5 = *reinterpret_cast<const __half2*>(&h[(size_t)s5 * DIM + 2 * l]);
            __half2 a6 = *reinterpret_cast<const __half2*>(&h[(size_t)s6 * DIM + 2 * l]);
            __half2 a7 = *reinterpret_cast<const __half2*>(&h[(size_t)s7 * DIM + 2 * l]);
            float2 f0 = __half22float2(a0);
            float2 f1 = __half22float2(a1);
            float2 f2 = __half22float2(a2);
            float2 f3 = __half22float2(a3);
            float2 f4 = __half22float2(a4);
            float2 f5 = __half22float2(a5);
            float2 f6 = __half22float2(a6);
            float2 f7 = __half22float2(a7);
            accx = fmaf(w0, f0.x, accx); accy = fmaf(w0, f0.y, accy);
            accx = fmaf(w1, f1.x, accx); accy = fmaf(w1, f1.y, accy);
            accx = fmaf(w2, f2.x, accx); accy = fmaf(w2, f2.y, accy);
            accx = fmaf(w3, f3.x, accx); accy = fmaf(w3, f3.y, accy);
            accx = fmaf(w4, f4.x, accx); accy = fmaf(w4, f4.y, accy);
            accx = fmaf(w5, f5.x, accx); accy = fmaf(w5, f5.y, accy);
            accx = fmaf(w6, f6.x, accx); accy = fmaf(w6, f6.y, accy);
            accx = fmaf(w7, f7.x, accx); accy = fmaf(w7, f7.y, accy);
        }
    }
    float inv = 1.f / ssum;
    float ox = accx * inv + bias[2 * l];
    float oy = accy * inv + bias[2 * l + 1];
    if constexpr (FP16OUT) {
        __half* out = (__half*)out_;
        *reinterpret_cast<__half2*>(&out[(size_t)node * DIM + 2 * l]) =
            __floats2half2_rn(ox, oy);
    } else {
        float* out = (float*)out_;
        *reinterpret_cast<float2*>(&out[(size_t)node * DIM + 2 * l]) =
            make_float2(ox, oy);
    }
}

extern "C" void kernel_launch(void* const* d_in, const int* in_sizes, int n_in,
                              void* d_out, int out_size, void* d_ws, size_t ws_size,
                              hipStream_t stream) {
    const float* x = (const float*)d_in[0];
    const int* ei = (const int*)d_in[1];   // harness converts integer inputs to int32
    const int n = out_size / DIM;          // 100000
    const int E = in_sizes[1] / 2;         // 1600000
    const int total_edges = E + n;
    const int NCB = (n + CBSZ - 1) >> CBSH;      // 196 coarse buckets (<=256)
    const int NPB = (E + CHUNK - 1) / CHUNK;     // 391 partition blocks (<=512)

    const float *W[3], *as_[3], *ad_[3], *b[3];
    for (int l = 0; l < 3; ++l) {
        W[l]  = (const float*)d_in[2 + 4 * l];
        as_[l] = (const float*)d_in[3 + 4 * l];
        ad_[l] = (const float*)d_in[4 + 4 * l];
        b[l]  = (const float*)d_in[5 + 4 * l];
    }

    // workspace carve (256B aligned).
    char* ws = (char*)d_ws;
    size_t off = 0;
    auto alloc = [&](size_t bytes) {
        void* p = ws + off;
        off = (off + bytes + 255) & ~(size_t)255;
        return p;
    };
    int* row_ptr  = (int*)alloc((size_t)(n + 1) * 4);
    int* hist2d   = (int*)alloc((size_t)NCB * NPB * 4);
    int* btot     = (int*)alloc(256 * 4);
    int* ebase    = (int*)alloc(257 * 4);
    int* csr      = (int*)alloc((size_t)total_edges * 4);
    int* part     = (int*)alloc((size_t)E * 4);
    __half* h     = (__half*)alloc((size_t)n * DIM * 2);
    __half* bufh  = (__half*)alloc((size_t)n * DIM * 2);  // fp16 inter-layer acts
    float* als    = (float*)alloc((size_t)n * 4);
    float* ald    = (float*)alloc((size_t)n * 4);

    // ---- CSR build (once; shared by all 3 layers) ----
    k_part_hist<<<NPB, 256, 0, stream>>>(ei, hist2d, E, NPB, NCB);
    k_part_scan<<<NCB, 512, 0, stream>>>(hist2d, btot, NPB);
    k_ebase<<<1, 256, 0, stream>>>(btot, ebase, row_ptr, NCB, n, E);
    k_part_scatter<<<NPB, 256, 0, stream>>>(ei, hist2d, ebase, part, E, NPB, NCB);
    k_bucket_scatter<<<NCB, 256, 0, stream>>>(ebase, part, row_ptr, csr, n);

    // ---- 3 GAT layers ----
    const int aggr_blocks = (n + 7) / 8;   // 8 nodes (half-waves) per 256-thread block
    const int gemm_blocks = (n + 63) / 64;

    // layer 0: fp32 input (no relu) -> fp16 activations
    k_gemm_al<128, false><<<gemm_blocks, 256, 0, stream>>>(
        x, W[0], as_[0], ad_[0], h, als, ald, n);
    k_node_aggr<true><<<aggr_blocks, 256, 0, stream>>>(
        row_ptr, csr, als, ald, h, b[0], bufh, n);
    // layer 1: fp16 input (relu folded) -> fp16 activations
    k_gemm_al<64, true><<<gemm_blocks, 256, 0, stream>>>(
        bufh, W[1], as_[1], ad_[1], h, als, ald, n);
    k_node_aggr<true><<<aggr_blocks, 256, 0, stream>>>(
        row_ptr, csr, als, ald, h, b[1], bufh, n);
    // layer 2: fp16 input (relu folded) -> fp32 d_out
    k_gemm_al<64, true><<<gemm_blocks, 256, 0, stream>>>(
        bufh, W[2], as_[2], ad_[2], h, als, ald, n);
    k_node_aggr<false><<<aggr_blocks, 256, 0, stream>>>(
        row_ptr, csr, als, ald, h, b[2], d_out, n);
}